// Round 4
// baseline (1136.799 us; speedup 1.0000x reference)
//
#include <hip/hip_runtime.h>

#define DD 4096
#define MM 1024
#define LL 8192
#define NBLK 512  // 2 blocks/CU guaranteed resident via __launch_bounds__(256,2)

// ---------------------------------------------------------------------------
// Device-wide sense-reversing barrier. All NBLK blocks are co-resident
// (512 blocks, 256 thr, >=2 waves/EU bound -> >=2 blocks/CU * 256 CUs).
// Device-scope atomics + __threadfence for cross-XCD visibility (G16).
// cnt/gen live in ws and are zeroed by hipMemsetAsync before launch.
// ---------------------------------------------------------------------------
__device__ __forceinline__ void grid_barrier(unsigned* cnt, unsigned* gen) {
    __syncthreads();
    __threadfence();  // release this block's global writes to device scope
    if (threadIdx.x == 0) {
        unsigned g = __hip_atomic_load(gen, __ATOMIC_RELAXED, __HIP_MEMORY_SCOPE_AGENT);
        unsigned a = __hip_atomic_fetch_add(cnt, 1u, __ATOMIC_ACQ_REL, __HIP_MEMORY_SCOPE_AGENT);
        if (a == NBLK - 1) {
            __hip_atomic_store(cnt, 0u, __ATOMIC_RELAXED, __HIP_MEMORY_SCOPE_AGENT);
            __hip_atomic_fetch_add(gen, 1u, __ATOMIC_ACQ_REL, __HIP_MEMORY_SCOPE_AGENT);
        } else {
            while (__hip_atomic_load(gen, __ATOMIC_ACQUIRE, __HIP_MEMORY_SCOPE_AGENT) == g) {
                __builtin_amdgcn_s_sleep(8);
            }
        }
    }
    __syncthreads();
    __threadfence();  // acquire side: don't read stale cached data
}

// Wave-per-row dot: row dot x over N4 float4 elements; result valid in lane 0.
template <int N4>
__device__ __forceinline__ float wave_row_dot(const float4* __restrict__ Arow,
                                              const float4* __restrict__ x4,
                                              int lane) {
    float ax = 0.f, ay = 0.f, az = 0.f, aw = 0.f;
#pragma unroll 8
    for (int k = lane; k < N4; k += 64) {
        float4 a = Arow[k];
        float4 b = x4[k];
        ax = fmaf(a.x, b.x, ax);
        ay = fmaf(a.y, b.y, ay);
        az = fmaf(a.z, b.z, az);
        aw = fmaf(a.w, b.w, aw);
    }
    float acc = (ax + ay) + (az + aw);
#pragma unroll
    for (int off = 32; off; off >>= 1) acc += __shfl_down(acc, off, 64);
    return acc;
}

// ---------------------------------------------------------------------------
// Whole pipeline in one kernel (6 stages, 5 grid barriers):
//  S1 s_q = F_q @ query                         (134 MB)
//  S2 zacc/sqacc column partials over mem       (17 MB)
//  S3 softmax + fold 1/||col||  -> qv           (block 0 only)
//  S4 u = mem @ qv                              (17 MB, L3-hot after S2)
//  S5 v = prelu(s_q + H @ u)                    (67 MB)
//  S6 out = R @ v                               (67 MB)
// Math note: the (1+sigmoid) column scale cancels under column L2-norm,
// so F_i/keys/U/V/W/a_mem/input are dead (verified passing in prior rounds).
// ---------------------------------------------------------------------------
__global__ __launch_bounds__(256, 2) void entnet_fused(
    const float* __restrict__ F_q, const float* __restrict__ query,
    const float* __restrict__ mem, const float* __restrict__ H,
    const float* __restrict__ R, const float* __restrict__ a_out,
    float* __restrict__ out, float* __restrict__ ws) {
    float* s_q = ws;                               // [4096]
    float* zacc = ws + 4096;                       // [1024] (memset 0)
    float* sqacc = ws + 5120;                      // [1024] (memset 0)
    unsigned* bar = (unsigned*)(ws + 6144);        // [2]    (memset 0)
    float* qv = ws + 6656;                         // [1024]
    float* u = ws + 7680;                          // [4096]
    float* v = ws + 11776;                         // [4096]

    const int b = blockIdx.x, tid = threadIdx.x;
    const int wave = tid >> 6, lane = tid & 63;
    __shared__ float sh3[4];
    __shared__ float red3[2];

    // ---- S1: s_q = F_q @ query (8 rows/block, 2 rows/wave) ----
    {
        const float4* x4 = reinterpret_cast<const float4*>(query);
#pragma unroll
        for (int i = 0; i < 2; ++i) {
            const int row = b * 8 + wave * 2 + i;
            float acc = wave_row_dot<LL / 4>(
                reinterpret_cast<const float4*>(F_q + (size_t)row * LL), x4, lane);
            if (lane == 0) s_q[row] = acc;
        }
    }
    grid_barrier(bar, bar + 1);

    // ---- S2: column partials (blocks 0..255, 16 rows each, float4 cols) ----
    if (b < 256) {
        const int r0 = b * 16;
        const float4* m4p = reinterpret_cast<const float4*>(mem);
        float z0 = 0.f, z1 = 0.f, z2 = 0.f, z3 = 0.f;
        float s0 = 0.f, s1 = 0.f, s2 = 0.f, s3 = 0.f;
#pragma unroll 4
        for (int r = 0; r < 16; ++r) {
            const float w = s_q[r0 + r];  // wave-uniform broadcast
            const float4 m4 = m4p[(size_t)(r0 + r) * (MM / 4) + tid];
            z0 = fmaf(w, m4.x, z0); s0 = fmaf(m4.x, m4.x, s0);
            z1 = fmaf(w, m4.y, z1); s1 = fmaf(m4.y, m4.y, s1);
            z2 = fmaf(w, m4.z, z2); s2 = fmaf(m4.z, m4.z, s2);
            z3 = fmaf(w, m4.w, z3); s3 = fmaf(m4.w, m4.w, s3);
        }
        atomicAdd(&zacc[4 * tid + 0], z0); atomicAdd(&zacc[4 * tid + 1], z1);
        atomicAdd(&zacc[4 * tid + 2], z2); atomicAdd(&zacc[4 * tid + 3], z3);
        atomicAdd(&sqacc[4 * tid + 0], s0); atomicAdd(&sqacc[4 * tid + 1], s1);
        atomicAdd(&sqacc[4 * tid + 2], s2); atomicAdd(&sqacc[4 * tid + 3], s3);
    }
    grid_barrier(bar, bar + 1);

    // ---- S3: softmax with folded 1/||col|| (block 0; 4 cols/thread) ----
    if (b == 0) {
        float t[4], rn[4], e[4];
        float mx = -1e30f;
#pragma unroll
        for (int j = 0; j < 4; ++j) {
            const int m = tid + 256 * j;
            rn[j] = rsqrtf(fmaxf(sqacc[m], 1e-24f));
            t[j] = zacc[m] * rn[j];
            mx = fmaxf(mx, t[j]);
        }
#pragma unroll
        for (int off = 32; off; off >>= 1) mx = fmaxf(mx, __shfl_down(mx, off, 64));
        if (lane == 0) sh3[wave] = mx;
        __syncthreads();
        if (tid == 0) red3[0] = fmaxf(fmaxf(sh3[0], sh3[1]), fmaxf(sh3[2], sh3[3]));
        __syncthreads();
        float ssum = 0.f;
#pragma unroll
        for (int j = 0; j < 4; ++j) { e[j] = __expf(t[j] - red3[0]); ssum += e[j]; }
#pragma unroll
        for (int off = 32; off; off >>= 1) ssum += __shfl_down(ssum, off, 64);
        if (lane == 0) sh3[wave] = ssum;
        __syncthreads();
        if (tid == 0) red3[1] = sh3[0] + sh3[1] + sh3[2] + sh3[3];
        __syncthreads();
        const float inv = 1.f / red3[1];
#pragma unroll
        for (int j = 0; j < 4; ++j) qv[tid + 256 * j] = e[j] * rn[j] * inv;
    }
    grid_barrier(bar, bar + 1);

    // ---- S4: u = mem @ qv ----
    {
        const float4* x4 = reinterpret_cast<const float4*>(qv);
#pragma unroll
        for (int i = 0; i < 2; ++i) {
            const int row = b * 8 + wave * 2 + i;
            float acc = wave_row_dot<MM / 4>(
                reinterpret_cast<const float4*>(mem + (size_t)row * MM), x4, lane);
            if (lane == 0) u[row] = acc;
        }
    }
    grid_barrier(bar, bar + 1);

    // ---- S5: v = prelu(s_q + H @ u) ----
    {
        const float4* x4 = reinterpret_cast<const float4*>(u);
        const float slope = a_out[0];
#pragma unroll
        for (int i = 0; i < 2; ++i) {
            const int row = b * 8 + wave * 2 + i;
            float acc = wave_row_dot<DD / 4>(
                reinterpret_cast<const float4*>(H + (size_t)row * DD), x4, lane);
            if (lane == 0) {
                float t = s_q[row] + acc;
                v[row] = (t >= 0.f) ? t : slope * t;
            }
        }
    }
    grid_barrier(bar, bar + 1);

    // ---- S6: out = R @ v ----
    {
        const float4* x4 = reinterpret_cast<const float4*>(v);
#pragma unroll
        for (int i = 0; i < 2; ++i) {
            const int row = b * 8 + wave * 2 + i;
            float acc = wave_row_dot<DD / 4>(
                reinterpret_cast<const float4*>(R + (size_t)row * DD), x4, lane);
            if (lane == 0) out[row] = acc;
        }
    }
}

extern "C" void kernel_launch(void* const* d_in, const int* in_sizes, int n_in,
                              void* d_out, int out_size, void* d_ws, size_t ws_size,
                              hipStream_t stream) {
    // inputs: 0 input, 1 query, 2 F_i, 3 F_q, 4 keys, 5 memory_nodes,
    //         6 U, 7 V, 8 W, 9 R, 10 H, 11 a_mem, 12 a_out
    const float* query = (const float*)d_in[1];
    const float* F_q   = (const float*)d_in[3];
    const float* mem   = (const float*)d_in[5];
    const float* R     = (const float*)d_in[9];
    const float* H     = (const float*)d_in[10];
    const float* a_out = (const float*)d_in[12];
    float* out = (float*)d_out;
    float* ws  = (float*)d_ws;

    // zero zacc[1024] + sqacc[1024] + barrier cnt/gen (contiguous: 2050 words)
    hipMemsetAsync(ws + 4096, 0, 2050 * sizeof(float), stream);

    entnet_fused<<<NBLK, 256, 0, stream>>>(F_q, query, mem, H, R, a_out, out, ws);
}

// Round 7
// 562.321 us; speedup vs baseline: 2.0216x; 2.0216x over previous
//
#include <hip/hip_runtime.h>

#define DD 4096
#define MM 1024
#define LL 8192
#define NBLK 512  // 2 blocks/CU via __launch_bounds__(256,2) -> all co-resident

// ---------------------------------------------------------------------------
// Coherent (agent-scope, relaxed) scalar access for cross-XCD handoff of the
// small intermediates. These take the L2-bypassing coherent path (sc1), so NO
// fences / L2 flushes are needed anywhere. Big read-only matrices keep normal
// cached loads.
// ---------------------------------------------------------------------------
__device__ __forceinline__ void st_c(float* p, float v) {
    __hip_atomic_store(p, v, __ATOMIC_RELAXED, __HIP_MEMORY_SCOPE_AGENT);
}
__device__ __forceinline__ float ld_c(const float* p) {
    return __hip_atomic_load(p, __ATOMIC_RELAXED, __HIP_MEMORY_SCOPE_AGENT);
}

// ---------------------------------------------------------------------------
// Fence-free grid barrier. Correctness argument:
//  - every wave's outstanding stores (incl. coherent sc1 stores and atomics)
//    are drained by the s_waitcnt the compiler emits before s_barrier in
//    __syncthreads(); the explicit asm is a belt for thread 0's wave;
//  - arrival/poll use RELAXED agent atomics -> no per-poll L2 invalidate
//    (Round-4's 810us kernel was exactly this: ACQUIRE polls + threadfences
//    = per-block L2 wb/inv storms, VALUBusy 0.29%);
//  - consumers read intermediates via ld_c (coherent point), so no acquire
//    fence is required for data visibility.
// ---------------------------------------------------------------------------
__device__ __forceinline__ void grid_barrier(unsigned* cnt, unsigned* gen) {
    __syncthreads();
    if (threadIdx.x == 0) {
        asm volatile("s_waitcnt vmcnt(0) lgkmcnt(0)" ::: "memory");
        unsigned g = __hip_atomic_load(gen, __ATOMIC_RELAXED, __HIP_MEMORY_SCOPE_AGENT);
        unsigned a = __hip_atomic_fetch_add(cnt, 1u, __ATOMIC_RELAXED, __HIP_MEMORY_SCOPE_AGENT);
        if (a == NBLK - 1) {
            __hip_atomic_store(cnt, 0u, __ATOMIC_RELAXED, __HIP_MEMORY_SCOPE_AGENT);
            __hip_atomic_fetch_add(gen, 1u, __ATOMIC_RELAXED, __HIP_MEMORY_SCOPE_AGENT);
        } else {
            while (__hip_atomic_load(gen, __ATOMIC_RELAXED, __HIP_MEMORY_SCOPE_AGENT) == g) {
                __builtin_amdgcn_s_sleep(2);
            }
        }
    }
    __syncthreads();
}

// Wave-per-row dot over N4 float4 elems; result valid in lane 0.
// Works for global x (S1: query input) and LDS x (S4-S6 staged vectors).
template <int N4>
__device__ __forceinline__ float wave_row_dot(const float4* __restrict__ Arow,
                                              const float4* x4, int lane) {
    float ax = 0.f, ay = 0.f, az = 0.f, aw = 0.f;
#pragma unroll 8
    for (int k = lane; k < N4; k += 64) {
        float4 a = Arow[k];
        float4 b = x4[k];
        ax = fmaf(a.x, b.x, ax);
        ay = fmaf(a.y, b.y, ay);
        az = fmaf(a.z, b.z, az);
        aw = fmaf(a.w, b.w, aw);
    }
    float acc = (ax + ay) + (az + aw);
#pragma unroll
    for (int off = 32; off; off >>= 1) acc += __shfl_down(acc, off, 64);
    return acc;
}

// ---------------------------------------------------------------------------
// Whole pipeline, one kernel, 6 stages, 5 fence-free grid barriers:
//  S1 s_q = F_q @ query (134 MB)   S2 zacc/sqacc col partials (17 MB)
//  S3 softmax+norm-fold -> qv      S4 u = mem @ qv (17 MB, cache-hot)
//  S5 v = prelu(s_q + H @ u) (67 MB)   S6 out = R @ v (67 MB)
// Math: the (1+sigmoid) column scale cancels under column L2-norm, so
// F_i/keys/U/V/W/a_mem/input are dead (harness-verified in prior rounds).
// ---------------------------------------------------------------------------
__global__ __launch_bounds__(256, 2) void entnet_fused(
    const float* __restrict__ F_q, const float* __restrict__ query,
    const float* __restrict__ mem, const float* __restrict__ H,
    const float* __restrict__ R, const float* __restrict__ a_out,
    float* __restrict__ out, float* __restrict__ ws) {
    float* s_q = ws;                               // [4096]
    float* zacc = ws + 4096;                       // [1024] (memset 0)
    float* sqacc = ws + 5120;                      // [1024] (memset 0)
    unsigned* bar = (unsigned*)(ws + 6144);        // [2]    (memset 0)
    float* qv = ws + 6656;                         // [1024]
    float* u = ws + 7680;                          // [4096]
    float* v = ws + 11776;                         // [4096]

    const int b = blockIdx.x, tid = threadIdx.x;
    const int wave = tid >> 6, lane = tid & 63;
    __shared__ float4 xbuf4[DD / 4];               // 16 KB staging for x vectors
    float* xbuf = reinterpret_cast<float*>(xbuf4);
    __shared__ float sh3[4];
    __shared__ float red3[2];

    // ---- S1: s_q = F_q @ query (8 rows/block, 2 rows/wave; query is input,
    //          normal cached loads are fine) ----
    {
        const float4* x4 = reinterpret_cast<const float4*>(query);
#pragma unroll
        for (int i = 0; i < 2; ++i) {
            const int row = b * 8 + wave * 2 + i;
            float acc = wave_row_dot<LL / 4>(
                reinterpret_cast<const float4*>(F_q + (size_t)row * LL), x4, lane);
            if (lane == 0) st_c(&s_q[row], acc);
        }
    }
    grid_barrier(bar, bar + 1);

    // ---- S2: column partials (blocks 0..255, 16 rows each, float4 cols) ----
    if (b < 256) {
        const int r0 = b * 16;
        const float4* m4p = reinterpret_cast<const float4*>(mem);
        float z0 = 0.f, z1 = 0.f, z2 = 0.f, z3 = 0.f;
        float s0 = 0.f, s1 = 0.f, s2 = 0.f, s3 = 0.f;
#pragma unroll 4
        for (int r = 0; r < 16; ++r) {
            const float w = ld_c(&s_q[r0 + r]);  // same addr all lanes: 1 req/wave
            const float4 m4 = m4p[(size_t)(r0 + r) * (MM / 4) + tid];
            z0 = fmaf(w, m4.x, z0); s0 = fmaf(m4.x, m4.x, s0);
            z1 = fmaf(w, m4.y, z1); s1 = fmaf(m4.y, m4.y, s1);
            z2 = fmaf(w, m4.z, z2); s2 = fmaf(m4.z, m4.z, s2);
            z3 = fmaf(w, m4.w, z3); s3 = fmaf(m4.w, m4.w, s3);
        }
        atomicAdd(&zacc[4 * tid + 0], z0); atomicAdd(&zacc[4 * tid + 1], z1);
        atomicAdd(&zacc[4 * tid + 2], z2); atomicAdd(&zacc[4 * tid + 3], z3);
        atomicAdd(&sqacc[4 * tid + 0], s0); atomicAdd(&sqacc[4 * tid + 1], s1);
        atomicAdd(&sqacc[4 * tid + 2], s2); atomicAdd(&sqacc[4 * tid + 3], s3);
    }
    grid_barrier(bar, bar + 1);

    // ---- S3: softmax with folded 1/||col|| (block 0; 4 cols/thread) ----
    if (b == 0) {
        float t[4], rn[4], e[4];
        float mx = -1e30f;
#pragma unroll
        for (int j = 0; j < 4; ++j) {
            const int m = tid + 256 * j;
            rn[j] = rsqrtf(fmaxf(ld_c(&sqacc[m]), 1e-24f));
            t[j] = ld_c(&zacc[m]) * rn[j];
            mx = fmaxf(mx, t[j]);
        }
#pragma unroll
        for (int off = 32; off; off >>= 1) mx = fmaxf(mx, __shfl_down(mx, off, 64));
        if (lane == 0) sh3[wave] = mx;
        __syncthreads();
        if (tid == 0) red3[0] = fmaxf(fmaxf(sh3[0], sh3[1]), fmaxf(sh3[2], sh3[3]));
        __syncthreads();
        float ssum = 0.f;
#pragma unroll
        for (int j = 0; j < 4; ++j) { e[j] = __expf(t[j] - red3[0]); ssum += e[j]; }
#pragma unroll
        for (int off = 32; off; off >>= 1) ssum += __shfl_down(ssum, off, 64);
        if (lane == 0) sh3[wave] = ssum;
        __syncthreads();
        if (tid == 0) red3[1] = sh3[0] + sh3[1] + sh3[2] + sh3[3];
        __syncthreads();
        const float inv = 1.f / red3[1];
#pragma unroll
        for (int j = 0; j < 4; ++j) st_c(&qv[tid + 256 * j], e[j] * rn[j] * inv);
    }
    grid_barrier(bar, bar + 1);

    // ---- S4: u = mem @ qv  (qv staged to LDS via coherent loads) ----
    {
#pragma unroll
        for (int i = tid; i < MM; i += 256) xbuf[i] = ld_c(&qv[i]);
        __syncthreads();
#pragma unroll
        for (int i = 0; i < 2; ++i) {
            const int row = b * 8 + wave * 2 + i;
            float acc = wave_row_dot<MM / 4>(
                reinterpret_cast<const float4*>(mem + (size_t)row * MM), xbuf4, lane);
            if (lane == 0) st_c(&u[row], acc);
        }
    }
    grid_barrier(bar, bar + 1);

    // ---- S5: v = prelu(s_q + H @ u)  (u staged to LDS) ----
    {
        const float slope = a_out[0];
#pragma unroll
        for (int i = tid; i < DD; i += 256) xbuf[i] = ld_c(&u[i]);
        __syncthreads();
#pragma unroll
        for (int i = 0; i < 2; ++i) {
            const int row = b * 8 + wave * 2 + i;
            float acc = wave_row_dot<DD / 4>(
                reinterpret_cast<const float4*>(H + (size_t)row * DD), xbuf4, lane);
            if (lane == 0) {
                float t = ld_c(&s_q[row]) + acc;
                st_c(&v[row], (t >= 0.f) ? t : slope * t);
            }
        }
    }
    grid_barrier(bar, bar + 1);

    // ---- S6: out = R @ v  (v staged to LDS; out via normal stores,
    //          end-of-kernel release handles host visibility) ----
    {
        __syncthreads();  // xbuf reuse: S5 readers done before overwrite
#pragma unroll
        for (int i = tid; i < DD; i += 256) xbuf[i] = ld_c(&v[i]);
        __syncthreads();
#pragma unroll
        for (int i = 0; i < 2; ++i) {
            const int row = b * 8 + wave * 2 + i;
            float acc = wave_row_dot<DD / 4>(
                reinterpret_cast<const float4*>(R + (size_t)row * DD), xbuf4, lane);
            if (lane == 0) out[row] = acc;
        }
    }
}

extern "C" void kernel_launch(void* const* d_in, const int* in_sizes, int n_in,
                              void* d_out, int out_size, void* d_ws, size_t ws_size,
                              hipStream_t stream) {
    // inputs: 0 input, 1 query, 2 F_i, 3 F_q, 4 keys, 5 memory_nodes,
    //         6 U, 7 V, 8 W, 9 R, 10 H, 11 a_mem, 12 a_out
    const float* query = (const float*)d_in[1];
    const float* F_q   = (const float*)d_in[3];
    const float* mem   = (const float*)d_in[5];
    const float* R     = (const float*)d_in[9];
    const float* H     = (const float*)d_in[10];
    const float* a_out = (const float*)d_in[12];
    float* out = (float*)d_out;
    float* ws  = (float*)d_ws;

    // zero zacc[1024] + sqacc[1024] + barrier cnt/gen (contiguous: 2050 words)
    hipMemsetAsync(ws + 4096, 0, 2050 * sizeof(float), stream);

    entnet_fused<<<NBLK, 256, 0, stream>>>(F_q, query, mem, H, R, a_out, out, ws);
}